// Round 1
// 376.909 us; speedup vs baseline: 1.0155x; 1.0155x over previous
//
#include <hip/hip_runtime.h>
#include <hip/hip_bf16.h>

// ---------------------------------------------------------------------------
// RecursiveSortNet — bf16 MFMA pipeline, u16-key packed bitonic sort:
//   sort: round x to bf16 (monotone => commutes with sort), map to
//         order-preserving u16 keys, 3x bitonic-64 with v_pk_min/max_u16
//   h1 = relu(xs @ W1^T + b1)   bf16 MFMA, fp32 acc
//   h2 = relu(h1 @ W2^T + b2)
//   out =      h2 @ W3^T + b3   fp32 out
//
// R1 change: waves in sort_kernel are fully independent (exclusive LDS
// slices) — replaced all 8 __syncthreads() with intra-wave
// s_waitcnt lgkmcnt(0) (+"memory" clobber). Removes cross-wave barrier
// convoy + vmcnt drain; waves' stalls decorrelate.
// ---------------------------------------------------------------------------

#define B_DIM 8192
#define D_DIM 4096
#define H1_DIM 512
#define H2_DIM 256

typedef unsigned short u16;
typedef __attribute__((ext_vector_type(2))) unsigned short u16x2;
typedef __attribute__((ext_vector_type(2))) short i16x2;
typedef __attribute__((ext_vector_type(8))) short bf16x8;
typedef __attribute__((ext_vector_type(4))) float f32x4;

// Intra-wave LDS ordering: all prior DS ops complete before any later DS op
// issues; "memory" clobber stops compiler reordering across the point.
// (No cross-wave rendezvous — waves own disjoint LDS slices.)
#define WAVE_SYNC() asm volatile("s_waitcnt lgkmcnt(0)" ::: "memory")

__device__ __forceinline__ unsigned short f2bf(float f) {
    union { float f; unsigned u; } v{f};
    unsigned r = v.u + 0x7FFF + ((v.u >> 16) & 1);   // RNE, finite inputs
    return (unsigned short)(r >> 16);
}
// bf16 bits -> order-preserving u16 key
__device__ __forceinline__ u16 fkey(float f) {
    u16 bf = f2bf(f);
    u16 m  = (u16)(((short)bf) >> 15);               // 0xFFFF if negative
    return (u16)(bf ^ (m | 0x8000));
}
__device__ __forceinline__ u16x2 mk2(u16 a, u16 b) { u16x2 r; r.x = a; r.y = b; return r; }

#if defined(__has_builtin) && __has_builtin(__builtin_elementwise_min)
__device__ __forceinline__ u16x2 pkmin(u16x2 a, u16x2 b) { return __builtin_elementwise_min(a, b); }
__device__ __forceinline__ u16x2 pkmax(u16x2 a, u16x2 b) { return __builtin_elementwise_max(a, b); }
#else
__device__ __forceinline__ u16x2 pkmin(u16x2 a, u16x2 b) {
    return mk2(a.x < b.x ? a.x : b.x, a.y < b.y ? a.y : b.y);
}
__device__ __forceinline__ u16x2 pkmax(u16x2 a, u16x2 b) {
    return mk2(a.x > b.x ? a.x : b.x, a.y > b.y ? a.y : b.y);
}
#endif

// Bitonic sort of 64 u16 keys held as 32 packed regs, reg p = (elem p, elem p+32).
// For j<32 partners are in distinct regs (packed CE); j==32 is the in-reg stage.
// Direction is per-slot uniform except the k==32 phase (slot y descending).
__device__ __forceinline__ void sortnet(u16x2 v[32]) {
#pragma unroll
    for (int k = 2; k <= 64; k <<= 1) {
#pragma unroll
        for (int j = k >> 1; j >= 1; j >>= 1) {
            if (j == 32) {                     // k==64 only, ascending
#pragma unroll
                for (int p = 0; p < 32; ++p) {
                    u16x2 sw = mk2(v[p].y, v[p].x);
                    u16x2 mn = pkmin(v[p], sw), mx = pkmax(v[p], sw);
                    v[p] = mk2(mn.x, mx.y);
                }
            } else {
#pragma unroll
                for (int p = 0; p < 32; ++p) {
                    if (p & j) continue;
                    const int q = p | j;
                    const bool upx = ((p & k) == 0);
                    const bool upy = (((p + 32) & k) == 0);  // differs only at k==32
                    u16x2 mn = pkmin(v[p], v[q]), mx = pkmax(v[p], v[q]);
                    if (upx == upy) {
                        v[p] = upx ? mn : mx;
                        v[q] = upx ? mx : mn;
                    } else {                   // k==32: slot x asc, slot y desc
                        v[p] = mk2(mn.x, mx.y);
                        v[q] = mk2(mx.x, mn.y);
                    }
                }
            }
        }
    }
}

// 2 matrices per 128-thread block (1 per wave). LDS stride 66 u16 (all phases
// <=2-way bank aliasing == free). Row phases use a permuted row layout
// (dword p of row = elems (p, p+32)) matching the packed register mapping.
// Waves never share LDS -> no __syncthreads; intra-wave WAVE_SYNC only.
#define SRT 66
__global__ __launch_bounds__(128)
void sort_kernel(const float* __restrict__ x, u16* __restrict__ xs)
{
    __shared__ u16 smem[2 * 64 * SRT];
    const int wave = threadIdx.x >> 6;
    const int lane = threadIdx.x & 63;
    u16* s = smem + wave * 64 * SRT;
    const int b = blockIdx.x * 2 + wave;
    const float* src = x  + (size_t)b * D_DIM;
    u16*         dst = xs + (size_t)b * D_DIM;

    // ---- stage-in: coalesced float4 loads -> keys -> LDS standard layout ----
    float4 t[16];
#pragma unroll
    for (int qq = 0; qq < 16; ++qq)
        t[qq] = *(const float4*)(src + (qq * 64 + lane) * 4);
#pragma unroll
    for (int qq = 0; qq < 16; ++qq) {
        int f = qq * 64 + lane, r = f >> 4, c0 = (f & 15) * 4;
        *(u16x2*)&s[r * SRT + c0]     = mk2(fkey(t[qq].x), fkey(t[qq].y));
        *(u16x2*)&s[r * SRT + c0 + 2] = mk2(fkey(t[qq].z), fkey(t[qq].w));
    }
    WAVE_SYNC();

    // ---- sort 1: columns (lane = column) ----
    u16x2 v[32];
#pragma unroll
    for (int p = 0; p < 32; ++p)
        v[p] = mk2(s[p * SRT + lane], s[(p + 32) * SRT + lane]);
    sortnet(v);

    // transpose-write, permuted row layout: row i pos (lane&31)*2+(lane>>5)
    WAVE_SYNC();
    {
        const int pos = (lane & 31) * 2 + (lane >> 5);
#pragma unroll
        for (int p = 0; p < 32; ++p) {
            s[p * SRT + pos]        = v[p].x;
            s[(p + 32) * SRT + pos] = v[p].y;
        }
    }
    WAVE_SYNC();

    // ---- sort 2: rows (lane = row); b32 reads land packed correctly ----
#pragma unroll
    for (int p = 0; p < 32; ++p)
        v[p] = *(const u16x2*)&s[lane * SRT + p * 2];
    sortnet(v);

    // transpose-write, standard layout
    WAVE_SYNC();
#pragma unroll
    for (int p = 0; p < 32; ++p) {
        s[lane * SRT + p]      = v[p].x;
        s[lane * SRT + p + 32] = v[p].y;
    }
    WAVE_SYNC();

    // ---- sort 3: columns again ----
#pragma unroll
    for (int p = 0; p < 32; ++p)
        v[p] = mk2(s[p * SRT + lane], s[(p + 32) * SRT + lane]);
    sortnet(v);

    // unmap keys -> bf16 bits (packed)
#pragma unroll
    for (int p = 0; p < 32; ++p) {
        i16x2 sh = ((i16x2)v[p]) >> 15;        // 0xFFFF where key bit15 set (orig >=0)
        u16x2 m  = (u16x2)sh;
        u16x2 c8; c8.x = 0x8000; c8.y = 0x8000;
        v[p] = v[p] ^ ((~m) | c8);
    }

    // transpose-write standard, then coalesced bf16 row stores
    WAVE_SYNC();
#pragma unroll
    for (int p = 0; p < 32; ++p) {
        s[p * SRT + lane]        = v[p].x;
        s[(p + 32) * SRT + lane] = v[p].y;
    }
    WAVE_SYNC();
#pragma unroll
    for (int qq = 0; qq < 16; ++qq) {
        int f = qq * 64 + lane, r = f >> 4, c0 = (f & 15) * 4;
        u16x2 a = *(const u16x2*)&s[r * SRT + c0];
        u16x2 c = *(const u16x2*)&s[r * SRT + c0 + 2];
        ushort4 o; o.x = a.x; o.y = a.y; o.z = c.x; o.w = c.y;
        *(ushort4*)(dst + f * 4) = o;
    }
}

// ---------------- fp32 -> bf16 weight conversion ---------------------------
__global__ __launch_bounds__(256)
void cvt_bf16(const float* __restrict__ src, unsigned short* __restrict__ dst, int n4)
{
    int i = blockIdx.x * blockDim.x + threadIdx.x;
    if (i < n4) {
        float4 v = ((const float4*)src)[i];
        ushort4 o;
        o.x = f2bf(v.x); o.y = f2bf(v.y); o.z = f2bf(v.z); o.w = f2bf(v.w);
        ((ushort4*)dst)[i] = o;
    }
}

// ---------------- bf16 MFMA GEMM: C = act(A @ W^T + bias) ------------------
template<int BM, int BN, bool RELU, bool OUT_BF16>
__global__ __launch_bounds__(256, 2)
void gemm_mfma(const unsigned short* __restrict__ A,
               const unsigned short* __restrict__ Wt,
               const float* __restrict__ bias,
               void* __restrict__ Cout, int M, int N, int K)
{
    constexpr int BK  = 64;
    constexpr int WTM = BM / 2, WTN = BN / 2;
    constexpr int FM  = WTM / 16, FN = WTN / 16;
    __shared__ unsigned short sA[BM * BK];
    __shared__ unsigned short sB[BN * BK];

    const int tid  = threadIdx.x;
    const int wave = tid >> 6;
    const int lane = tid & 63;
    const int wm   = wave >> 1, wn = wave & 1;
    const int gm0  = blockIdx.y * BM;
    const int gn0  = blockIdx.x * BN;

    const int r_in = lane >> 3;
    const int j_in = lane & 7;

    f32x4 acc[FM][FN] = {};

    for (int k0 = 0; k0 < K; k0 += BK) {
#pragma unroll
        for (int c = 0; c < BM / 32; ++c) {
            int rb  = wave * (BM / 4) + c * 8;
            int r   = rb + r_in;
            int seg = j_in ^ (r & 7);
            const unsigned short* g = A + (size_t)(gm0 + r) * K + k0 + seg * 8;
            __builtin_amdgcn_global_load_lds(
                (const __attribute__((address_space(1))) void*)g,
                (__attribute__((address_space(3))) void*)&sA[rb * 64],
                16, 0, 0);
        }
#pragma unroll
        for (int c = 0; c < BN / 32; ++c) {
            int rb  = wave * (BN / 4) + c * 8;
            int r   = rb + r_in;
            int seg = j_in ^ (r & 7);
            const unsigned short* g = Wt + (size_t)(gn0 + r) * K + k0 + seg * 8;
            __builtin_amdgcn_global_load_lds(
                (const __attribute__((address_space(1))) void*)g,
                (__attribute__((address_space(3))) void*)&sB[rb * 64],
                16, 0, 0);
        }
        __syncthreads();

#pragma unroll
        for (int ks = 0; ks < 2; ++ks) {
            bf16x8 afr[FM], bfr[FN];
#pragma unroll
            for (int i = 0; i < FM; ++i) {
                int m   = wm * WTM + i * 16 + (lane & 15);
                int seg = (ks * 4 + (lane >> 4)) ^ (m & 7);
                afr[i] = *(const bf16x8*)&sA[m * 64 + seg * 8];
            }
#pragma unroll
            for (int j = 0; j < FN; ++j) {
                int n   = wn * WTN + j * 16 + (lane & 15);
                int seg = (ks * 4 + (lane >> 4)) ^ (n & 7);
                bfr[j] = *(const bf16x8*)&sB[n * 64 + seg * 8];
            }
#pragma unroll
            for (int i = 0; i < FM; ++i)
#pragma unroll
                for (int j = 0; j < FN; ++j)
                    acc[i][j] = __builtin_amdgcn_mfma_f32_16x16x32_bf16(
                        afr[i], bfr[j], acc[i][j], 0, 0, 0);
        }
        __syncthreads();
    }

#pragma unroll
    for (int j = 0; j < FN; ++j) {
        int n = gn0 + wn * WTN + j * 16 + (lane & 15);
        float bv = bias[n];
#pragma unroll
        for (int i = 0; i < FM; ++i) {
#pragma unroll
            for (int r = 0; r < 4; ++r) {
                int m = gm0 + wm * WTM + i * 16 + (lane >> 4) * 4 + r;
                float v = acc[i][j][r] + bv;
                if (RELU) v = fmaxf(v, 0.f);
                if (OUT_BF16)
                    ((unsigned short*)Cout)[(size_t)m * N + n] = f2bf(v);
                else
                    ((float*)Cout)[(size_t)m * N + n] = v;
            }
        }
    }
}

// ---------------------------------------------------------------------------
extern "C" void kernel_launch(void* const* d_in, const int* in_sizes, int n_in,
                              void* d_out, int out_size, void* d_ws, size_t ws_size,
                              hipStream_t stream)
{
    const float* x  = (const float*)d_in[0];
    const float* W1 = (const float*)d_in[1];
    const float* b1 = (const float*)d_in[2];
    const float* W2 = (const float*)d_in[3];
    const float* b2 = (const float*)d_in[4];
    const float* W3 = (const float*)d_in[5];
    const float* b3 = (const float*)d_in[6];
    float* out = (float*)d_out;

    // xs (bf16, 64 MB) lives in d_out; GEMM3 overwrites d_out after GEMM1 read xs.
    u16* xs = (u16*)d_out;
    char* ws = (char*)d_ws;
    unsigned short* h1b = (unsigned short*)(ws);                      //  8 MB
    unsigned short* h2b = (unsigned short*)(ws + (8u  << 20));        //  4 MB
    unsigned short* W1b = (unsigned short*)(ws + (12u << 20));        //  4 MB
    unsigned short* W2b = (unsigned short*)(ws + (16u << 20));        //  0.25 MB
    unsigned short* W3b = (unsigned short*)(ws + (17u << 20));        //  2 MB

    sort_kernel<<<B_DIM / 2, 128, 0, stream>>>(x, xs);

    cvt_bf16<<<(H1_DIM * D_DIM / 4 + 255) / 256, 256, 0, stream>>>(W1, W1b, H1_DIM * D_DIM / 4);
    cvt_bf16<<<(H2_DIM * H1_DIM / 4 + 255) / 256, 256, 0, stream>>>(W2, W2b, H2_DIM * H1_DIM / 4);
    cvt_bf16<<<(D_DIM * H2_DIM / 4 + 255) / 256, 256, 0, stream>>>(W3, W3b, D_DIM * H2_DIM / 4);

    // h1 = relu(xs @ W1^T + b1)  [8192 x 512, K=4096]  tile 128x64
    gemm_mfma<128, 64, true, true>
        <<<dim3(H1_DIM / 64, B_DIM / 128), 256, 0, stream>>>(
            xs, W1b, b1, h1b, B_DIM, H1_DIM, D_DIM);

    // h2 = relu(h1 @ W2^T + b2)  [8192 x 256, K=512]   tile 128x64
    gemm_mfma<128, 64, true, true>
        <<<dim3(H2_DIM / 64, B_DIM / 128), 256, 0, stream>>>(
            h1b, W2b, b2, h2b, B_DIM, H2_DIM, H1_DIM);

    // out = h2 @ W3^T + b3       [8192 x 4096, K=256]  tile 128x128
    gemm_mfma<128, 128, false, false>
        <<<dim3(D_DIM / 128, B_DIM / 128), 256, 0, stream>>>(
            h2b, W3b, b3, out, B_DIM, D_DIM, H2_DIM);
}